// Round 2
// baseline (246.053 us; speedup 1.0000x reference)
//
#include <hip/hip_runtime.h>
#include <hip/hip_bf16.h>
#include <stdint.h>

typedef int v4i __attribute__((ext_vector_type(4)));

#define TOK 8192   // B*S
#define DIN 4096   // K
#define DOUT 4096  // N

#define BM 128
#define BN 128
#define BKB 64  // K-bytes per LDS tile (int8)

// ---------------- Kernel 1: per-token dynamic quantization ----------------
// One block (256 threads) per token row of 4096 fp32. Each thread holds 16
// floats in registers (4x float4), computes absmax via shfl+LDS reduce, then
// quantizes from registers (no second global read).
__global__ __launch_bounds__(256) void quant_rows(const float* __restrict__ x,
                                                  int8_t* __restrict__ xq,
                                                  float* __restrict__ ascale) {
    const int row = blockIdx.x;
    const int t = threadIdx.x;
    const float* __restrict__ xr = x + (size_t)row * DIN;
    float4 v[4];
    float amax = 0.0f;
#pragma unroll
    for (int i = 0; i < 4; ++i) {
        v[i] = reinterpret_cast<const float4*>(xr)[t + 256 * i];
        amax = fmaxf(amax, fmaxf(fmaxf(fabsf(v[i].x), fabsf(v[i].y)),
                                 fmaxf(fabsf(v[i].z), fabsf(v[i].w))));
    }
#pragma unroll
    for (int off = 1; off < 64; off <<= 1)
        amax = fmaxf(amax, __shfl_xor(amax, off, 64));
    __shared__ float wmax[4];
    if ((t & 63) == 0) wmax[t >> 6] = amax;
    __syncthreads();
    amax = fmaxf(fmaxf(wmax[0], wmax[1]), fmaxf(wmax[2], wmax[3]));
    // exact reference semantics: scale = max(absmax, 1e-8) / 127 (IEEE div)
    const float scale = fmaxf(amax, 1e-8f) / 127.0f;
    if (t == 0) ascale[row] = scale;
    uint32_t* __restrict__ qr = reinterpret_cast<uint32_t*>(xq + (size_t)row * DIN);
#pragma unroll
    for (int i = 0; i < 4; ++i) {
        // IEEE division + rintf == jnp.round(x / act_scale) (half-to-even)
        int q0 = (int)fminf(fmaxf(rintf(v[i].x / scale), -128.0f), 127.0f);
        int q1 = (int)fminf(fmaxf(rintf(v[i].y / scale), -128.0f), 127.0f);
        int q2 = (int)fminf(fmaxf(rintf(v[i].z / scale), -128.0f), 127.0f);
        int q3 = (int)fminf(fmaxf(rintf(v[i].w / scale), -128.0f), 127.0f);
        qr[t + 256 * i] = (uint32_t)((q0 & 0xFF) | ((q1 & 0xFF) << 8) |
                                     ((q2 & 0xFF) << 16) | ((q3 & 0xFF) << 24));
    }
}

// ---------------- Kernel 2: weight repack int32 -> int8 ----------------
__global__ __launch_bounds__(256) void pack_w(const int* __restrict__ wq,
                                              uint32_t* __restrict__ w8) {
    const size_t i = (size_t)blockIdx.x * 256 + threadIdx.x;
    int4 a = reinterpret_cast<const int4*>(wq)[i];
    w8[i] = (uint32_t)((a.x & 0xFF) | ((a.y & 0xFF) << 8) |
                       ((a.z & 0xFF) << 16) | ((a.w & 0xFF) << 24));
}

// ---------------- Kernel 3: int8 GEMM (m97 structure) ----------------
// C[M][N] = A[M][K] * B[N][K]^T, exact int32 accumulate via
// mfma_i32_16x16x64_i8, fused dequant epilogue:
//   y = acc * ascale[m] * wscale[n] + bias[n]
__global__ __launch_bounds__(256) void gemm_i8(const int8_t* __restrict__ A,
                                               const int8_t* __restrict__ B,
                                               const float* __restrict__ ascale,
                                               const float* __restrict__ wscale,
                                               const float* __restrict__ bias,
                                               float* __restrict__ C) {
    __shared__ int8_t As[2][BM * BKB];
    __shared__ int8_t Bs[2][BM * BKB];
    const int tid = threadIdx.x;
    const int bn = blockIdx.x, bm = blockIdx.y;

    const int srow = tid >> 2;        // 0..63 staging row
    const int scol = (tid & 3) * 16;  // staging col byte

    const int8_t* ga = A + (size_t)(bm * BM + srow) * DIN + scol;
    const int8_t* gb = B + (size_t)(bn * BN + srow) * DIN + scol;

#define STAGE(buf, k0)                                                                       \
    do {                                                                                     \
        __builtin_amdgcn_global_load_lds(                                                    \
            (const __attribute__((address_space(1))) void*)(ga + (k0)),                      \
            (__attribute__((address_space(3))) void*)(&As[buf][tid * 16]), 16, 0, 0);        \
        __builtin_amdgcn_global_load_lds(                                                    \
            (const __attribute__((address_space(1))) void*)(ga + (size_t)64 * DIN + (k0)),   \
            (__attribute__((address_space(3))) void*)(&As[buf][4096 + tid * 16]), 16, 0, 0); \
        __builtin_amdgcn_global_load_lds(                                                    \
            (const __attribute__((address_space(1))) void*)(gb + (k0)),                      \
            (__attribute__((address_space(3))) void*)(&Bs[buf][tid * 16]), 16, 0, 0);        \
        __builtin_amdgcn_global_load_lds(                                                    \
            (const __attribute__((address_space(1))) void*)(gb + (size_t)64 * DIN + (k0)),   \
            (__attribute__((address_space(3))) void*)(&Bs[buf][4096 + tid * 16]), 16, 0, 0); \
    } while (0)

    const int w = tid >> 6;
    const int l = tid & 63;
    const int wm = (w >> 1) * 64;  // wave 2x2 grid, each wave 64x64 output
    const int wn = (w & 1) * 64;
    const int lr = l & 15;         // A row / B col within fragment
    const int lk = (l >> 4) * 16;  // k-byte offset within fragment

    v4i acc[4][4];
#pragma unroll
    for (int i = 0; i < 4; ++i)
#pragma unroll
        for (int j = 0; j < 4; ++j) acc[i][j] = (v4i){0, 0, 0, 0};

    STAGE(0, 0);
    __syncthreads();
    int cur = 0;
    const int NT = DIN / BKB;  // 64
    for (int kt = 0; kt < NT; ++kt) {
        if (kt + 1 < NT) STAGE(cur ^ 1, (kt + 1) * BKB);
        v4i af[4], bf[4];
#pragma unroll
        for (int f = 0; f < 4; ++f) {
            af[f] = *reinterpret_cast<const v4i*>(&As[cur][(wm + f * 16 + lr) * BKB + lk]);
            bf[f] = *reinterpret_cast<const v4i*>(&Bs[cur][(wn + f * 16 + lr) * BKB + lk]);
        }
#pragma unroll
        for (int fm = 0; fm < 4; ++fm)
#pragma unroll
            for (int fn = 0; fn < 4; ++fn)
                acc[fm][fn] = __builtin_amdgcn_mfma_i32_16x16x64_i8(af[fm], bf[fn],
                                                                    acc[fm][fn], 0, 0, 0);
        __syncthreads();
        cur ^= 1;
    }

    // Epilogue: C/D layout col=lane&15, row=(lane>>4)*4+reg (dtype-independent)
    const int col0 = bn * BN + wn + lr;
    float wsv[4], bbv[4];
#pragma unroll
    for (int fn = 0; fn < 4; ++fn) {
        wsv[fn] = wscale[col0 + fn * 16];
        bbv[fn] = bias[col0 + fn * 16];
    }
    const int rbase = bm * BM + wm + (l >> 4) * 4;
#pragma unroll
    for (int fm = 0; fm < 4; ++fm) {
#pragma unroll
        for (int r = 0; r < 4; ++r) {
            const int row = rbase + fm * 16 + r;
            const float as = ascale[row];
            float* __restrict__ crow = C + (size_t)row * DOUT;
#pragma unroll
            for (int fn = 0; fn < 4; ++fn) {
                crow[col0 + fn * 16] = (float)acc[fm][fn][r] * as * wsv[fn] + bbv[fn];
            }
        }
    }
#undef STAGE
}

extern "C" void kernel_launch(void* const* d_in, const int* in_sizes, int n_in,
                              void* d_out, int out_size, void* d_ws, size_t ws_size,
                              hipStream_t stream) {
    const float* x = (const float*)d_in[0];
    const int* wq = (const int*)d_in[1];
    const float* wscale = (const float*)d_in[2];
    const float* bias = (const float*)d_in[3];
    float* out = (float*)d_out;

    // workspace layout: xq[TOK*DIN] int8 | w8[DOUT*DIN] int8 | ascale[TOK] f32
    int8_t* xq = (int8_t*)d_ws;
    int8_t* w8 = xq + (size_t)TOK * DIN;
    float* ascale = (float*)(w8 + (size_t)DOUT * DIN);

    quant_rows<<<TOK, 256, 0, stream>>>(x, xq, ascale);
    pack_w<<<(int)(((size_t)DOUT * DIN / 4) / 256), 256, 0, stream>>>(wq, (uint32_t*)w8);
    gemm_i8<<<dim3(DOUT / BN, TOK / BM), 256, 0, stream>>>(xq, w8, ascale, wscale, bias, out);
}